// Round 4
// baseline (576.774 us; speedup 1.0000x reference)
//
#include <hip/hip_runtime.h>

// ScaledConvolutionalDotProduct: B=4, S=2048, D=1024
//   qp = relu(q@Wq + bq); kp = relu(k@Wk + bk); vp = relu(v@Wv + bv)
//   logits = relu(qp@kp^T)/32 + mask;  out = relu(logits@vp)
// Round 4: BK=32 4-phase GEMM, 2-3 blocks/CU occupancy (48-64KB LDS),
//          exact-2-way LDS swizzle, L2-aware per-XCD block ordering.

#define B_ 4
#define S_ 2048
#define D_ 1024

typedef __attribute__((ext_vector_type(8))) short short8;
typedef __attribute__((ext_vector_type(4))) float f32x4;
typedef const __attribute__((address_space(1))) void* gas1;
typedef __attribute__((address_space(3))) void* las3;

template <int V> struct IC { static constexpr int value = V; };

static __device__ __forceinline__ short f2bf(float x) {
    union { float f; unsigned u; } un; un.f = x;
    unsigned r = un.u + 0x7fff + ((un.u >> 16) & 1);
    return (short)(r >> 16);
}

// ---------------- fp32 -> bf16 convert, q/k/v fused (8 elems/thread) ----------------
__global__ void cvt3_kernel(const float* __restrict__ q, const float* __restrict__ k,
                            const float* __restrict__ v, short* __restrict__ out) {
    const float* in = (blockIdx.y == 0) ? q : ((blockIdx.y == 1) ? k : v);
    size_t i = ((size_t)blockIdx.x * blockDim.x + threadIdx.x) * 8;
    short* o = out + (size_t)blockIdx.y * ((size_t)B_ * S_ * D_);
    float4 a = *(const float4*)(in + i);
    float4 b = *(const float4*)(in + i + 4);
    short8 r;
    r[0] = f2bf(a.x); r[1] = f2bf(a.y); r[2] = f2bf(a.z); r[3] = f2bf(a.w);
    r[4] = f2bf(b.x); r[5] = f2bf(b.y); r[6] = f2bf(b.z); r[7] = f2bf(b.w);
    *(short8*)(o + i) = r;
}

// ---------------- W [d][e] fp32 -> W^T [e][d] bf16 ----------------
__global__ void make_wT_kernel(const float* __restrict__ Wq, const float* __restrict__ Wk,
                               const float* __restrict__ Wv, short* __restrict__ wT) {
    const float* W = (blockIdx.z == 0) ? Wq : ((blockIdx.z == 1) ? Wk : Wv);
    short* o = wT + (size_t)blockIdx.z * D_ * D_;
    __shared__ float t[32][33];
    int bx = blockIdx.x, by = blockIdx.y;
    int tx = threadIdx.x & 31, ty = threadIdx.x >> 5;   // 32 x 8
    #pragma unroll
    for (int r = ty; r < 32; r += 8)
        t[r][tx] = W[(size_t)(by * 32 + r) * D_ + bx * 32 + tx];
    __syncthreads();
    #pragma unroll
    for (int r = ty; r < 32; r += 8)
        o[(size_t)(bx * 32 + r) * D_ + by * 32 + tx] = f2bf(t[tx][r]);
}

// ---------------- vp [b][s][e] -> vpT [b][e][s] (bf16) ----------------
__global__ void transpose_bf16_kernel(const short* __restrict__ in, short* __restrict__ out) {
    __shared__ short t[64][65];
    int b = blockIdx.z;
    int e0 = blockIdx.x * 64, s0 = blockIdx.y * 64;
    const short* src = in + (size_t)b * S_ * D_;
    short* dst = out + (size_t)b * D_ * S_;
    int tx = threadIdx.x & 63, ty = threadIdx.x >> 6;   // 64 x 4
    #pragma unroll
    for (int r = ty; r < 64; r += 4)
        t[r][tx] = src[(size_t)(s0 + r) * D_ + e0 + tx];
    __syncthreads();
    #pragma unroll
    for (int r = ty; r < 64; r += 4)
        dst[(size_t)(e0 + r) * S_ + s0 + tx] = t[tx][r];
}

// ---------------- 4-phase BK=32 GEMM: C = epilogue(A * B^T), A:[M,K] B:[N,K] bf16 ----
// 8 waves (WM x WN), BM=16*M_REP*WM, BN=16*N_REP*WN, BK=32, double-buffered LDS.
// Swizzle: 16B slot ^= (row>>1)&3 (exact 2-way = free), applied source-side + read-side.
// Schedule/iter: ph1(par0,mh0,stage par1<-t1) ph2(par0,mh1,drain)
//                ph3(par1,mh0,stage par0<-t2) ph4(par1,mh1,drain)
// EPI 0: bf16 = relu(acc + bias[n])       (projections; bz selects bias)
// EPI 1: bf16 = relu(acc)/32 + mask[m][n] (scores)
// EPI 2: f32  = relu(acc)                 (PV)
template <int M_REP, int N_REP, int WM, int WN, int EPI>
__global__ __launch_bounds__(512, 4)
void gemm4p_kernel(const short* __restrict__ A, const short* __restrict__ B, void* __restrict__ Cv,
                   int K, int lda, int ldb, int ldc,
                   size_t sA, size_t sB, size_t sC,
                   const float* __restrict__ bias0, const float* __restrict__ bias1,
                   const float* __restrict__ bias2,
                   const float* __restrict__ mask, int ldmask) {
    constexpr int BM = 16 * M_REP * WM;      // 256
    constexpr int BN = 16 * N_REP * WN;      // 128 or 256
    constexpr int AR = (BM * 32 * 2) / 8192; // stage rounds (8KB per round, 512 thr x 16B)
    constexpr int BR = (BN * 32 * 2) / 8192;

    __shared__ short As[2][BM * 32];
    __shared__ short Bs[2][BN * 32];

    // L2-locality ordering: per-XCD contiguous id range, N-dim (by) innermost so the
    // GY blocks sharing one A-panel run back-to-back on one XCD. nwg % 8 == 0 required.
    const int GX = gridDim.x, GY = gridDim.y;
    const int nwg = GX * GY * gridDim.z;
    const int flat = blockIdx.x + GX * (blockIdx.y + GY * blockIdx.z);
    const int g = (flat & 7) * (nwg >> 3) + (flat >> 3);
    const int by = g % GY;
    const int strip = g / GY;
    const int bx = strip % GX;
    const int bz = strip / GX;

    const int m0 = bx * BM, n0 = by * BN;
    const short* Ab = A + (size_t)bz * sA;
    const short* Bb = B + (size_t)bz * sB;

    const int tid = threadIdx.x;
    const int lane = tid & 63;
    const int w = tid >> 6;                  // wave 0..7
    const int wc = w % WN, wr = w / WN;
    const int lr16 = lane & 15, kq = lane >> 4;
    const int NT = K >> 5;                   // K-tiles of 32 (always even here)

    // pre-swizzled source column (shorts): slot(t&3) ^ ((row>>1)&3) with row = t>>2
    const int csrc = (((tid & 3) ^ ((tid >> 3) & 3)) << 3);

    auto stageA = [&](int par, int kt) {
        if (kt >= NT) return;
        #pragma unroll
        for (int R = 0; R < AR; ++R) {
            int row = R * 128 + (tid >> 2);
            const short* src = Ab + (size_t)(m0 + row) * lda + kt * 32 + csrc;
            __builtin_amdgcn_global_load_lds((gas1)src, (las3)&As[par][R * 4096 + tid * 8], 16, 0, 0);
        }
    };
    auto stageB = [&](int par, int kt) {
        if (kt >= NT) return;
        #pragma unroll
        for (int R = 0; R < BR; ++R) {
            int row = R * 128 + (tid >> 2);
            const short* src = Bb + (size_t)(n0 + row) * ldb + kt * 32 + csrc;
            __builtin_amdgcn_global_load_lds((gas1)src, (las3)&Bs[par][R * 4096 + tid * 8], 16, 0, 0);
        }
    };
    // swizzled ds_read_b128 of one 16x32 MFMA fragment
    auto ldA = [&](int par, int mi) -> short8 {
        int row = wr * (16 * M_REP) + mi * 16 + lr16;
        int col = (kq ^ ((row >> 1) & 3)) << 3;
        return *(const short8*)&As[par][row * 32 + col];
    };
    auto ldB = [&](int par, int ni) -> short8 {
        int row = wc * (16 * N_REP) + ni * 16 + lr16;
        int col = (kq ^ ((row >> 1) & 3)) << 3;
        return *(const short8*)&Bs[par][row * 32 + col];
    };

    f32x4 acc[M_REP][N_REP] = {};
    short8 bfr[N_REP];

    // prologue: tile 0 -> par0
    stageA(0, 0); stageB(0, 0);
    asm volatile("s_waitcnt vmcnt(0)" ::: "memory");
    __builtin_amdgcn_s_barrier();

    auto phase = [&](int par, auto mhC, auto stageF, auto drainC) {
        constexpr int mh = decltype(mhC)::value;
        constexpr int drain = decltype(drainC)::value;
        short8 a[M_REP / 2];
        #pragma unroll
        for (int m = 0; m < M_REP / 2; ++m) a[m] = ldA(par, mh * (M_REP / 2) + m);
        if constexpr (mh == 0) {
            #pragma unroll
            for (int n = 0; n < N_REP; ++n) bfr[n] = ldB(par, n);
        }
        stageF();
        __builtin_amdgcn_s_barrier();
        asm volatile("s_waitcnt lgkmcnt(0)" ::: "memory");
        __builtin_amdgcn_sched_barrier(0);
        __builtin_amdgcn_s_setprio(1);
        #pragma unroll
        for (int m = 0; m < M_REP / 2; ++m)
            #pragma unroll
            for (int n = 0; n < N_REP; ++n)
                acc[mh * (M_REP / 2) + m][n] =
                    __builtin_amdgcn_mfma_f32_16x16x32_bf16(a[m], bfr[n],
                                                            acc[mh * (M_REP / 2) + m][n], 0, 0, 0);
        __builtin_amdgcn_s_setprio(0);
        if constexpr (drain) asm volatile("s_waitcnt vmcnt(0)" ::: "memory");
        __builtin_amdgcn_s_barrier();
    };

    #pragma unroll 1
    for (int I = 0; I < (NT >> 1); ++I) {
        phase(0, IC<0>{}, [&] { stageA(1, 2 * I + 1); stageB(1, 2 * I + 1); }, IC<0>{});
        phase(0, IC<1>{}, [&] {}, IC<1>{});
        phase(1, IC<0>{}, [&] { stageA(0, 2 * I + 2); stageB(0, 2 * I + 2); }, IC<0>{});
        phase(1, IC<1>{}, [&] {}, IC<1>{});
    }

    // epilogue: C/D layout col=lane&15, row=(lane>>4)*4+j  [m89-verified]
    short* Cs = (short*)Cv + (size_t)bz * sC;
    float* Cf = (float*)Cv + (size_t)bz * sC;
    const float* bias = (EPI == 0) ? ((bz == 0) ? bias0 : ((bz == 1) ? bias1 : bias2)) : nullptr;
    #pragma unroll
    for (int mi = 0; mi < M_REP; ++mi) {
        #pragma unroll
        for (int ni = 0; ni < N_REP; ++ni) {
            int n = n0 + wc * (16 * N_REP) + ni * 16 + lr16;
            int mb = m0 + wr * (16 * M_REP) + mi * 16 + kq * 4;
            #pragma unroll
            for (int j = 0; j < 4; ++j) {
                int m = mb + j;
                float val = acc[mi][ni][j];
                if constexpr (EPI == 0) {
                    val = fmaxf(val + bias[n], 0.f);
                    Cs[(size_t)m * ldc + n] = f2bf(val);
                } else if constexpr (EPI == 1) {
                    val = fmaxf(val, 0.f) * 0.03125f + mask[(size_t)m * ldmask + n];
                    Cs[(size_t)m * ldc + n] = f2bf(val);
                } else {
                    Cf[(size_t)m * ldc + n] = fmaxf(val, 0.f);
                }
            }
        }
    }
}

extern "C" void kernel_launch(void* const* d_in, const int* in_sizes, int n_in,
                              void* d_out, int out_size, void* d_ws, size_t ws_size,
                              hipStream_t stream) {
    const float* q    = (const float*)d_in[0];
    const float* k    = (const float*)d_in[1];
    const float* v    = (const float*)d_in[2];
    const float* mask = (const float*)d_in[3];
    const float* Wq   = (const float*)d_in[4];
    const float* Wk   = (const float*)d_in[5];
    const float* Wv   = (const float*)d_in[6];
    const float* bq   = (const float*)d_in[7];
    const float* bk   = (const float*)d_in[8];
    const float* bv   = (const float*)d_in[9];
    float* out = (float*)d_out;

    char* ws = (char*)d_ws;
    // layout (bytes):
    //   wT     @ 0          : 3*1024*1024*2   = 6,291,456
    //   qkv_bf @ 6,291,456  : 3*8192*1024*2   = 50,331,648  (dead after projections)
    //   logits @ 6,291,456  : 4*2048*2048*2   = 33,554,432  (overlay on qkv_bf)
    //   qkvp   @ 56,623,104 : 3*8192*1024*2   = 50,331,648  (qp|kp|vp)
    //   vpT    @ 56,623,104 : overlay on qp (qp dead after scores)
    //   total 106,954,752
    short* wT     = (short*)(ws);
    short* qkv_bf = (short*)(ws + 6291456);
    short* logits = (short*)(ws + 6291456);
    short* qkvp   = (short*)(ws + 56623104);
    short* qp     = qkvp;
    short* kp     = qkvp + (size_t)B_ * S_ * D_;
    short* vp     = qkvp + 2 * (size_t)B_ * S_ * D_;
    short* vpT    = qp;   // overlay (qp dead after scores)

    const size_t tok = (size_t)B_ * S_;            // 8192
    const size_t tokD = tok * D_;                  // 8,388,608

    // 1) W -> W^T bf16
    make_wT_kernel<<<dim3(32, 32, 3), 256, 0, stream>>>(Wq, Wk, Wv, wT);

    // 2) q/k/v -> bf16 (one fused launch)
    cvt3_kernel<<<dim3(tokD / 8 / 256, 3), 256, 0, stream>>>(q, k, v, qkv_bf);

    // 3) projections, batched z=3: qp/kp/vp = relu(x @ W + b)  [M=8192,N=1024,K=1024]
    //    BM=256 BN=128, warps 4x2, 48KB LDS -> 3 blocks/CU
    gemm4p_kernel<4, 4, 4, 2, 0><<<dim3(32, 8, 3), 512, 0, stream>>>(
        qkv_bf, wT, qkvp, D_, D_, D_, D_,
        tokD, (size_t)D_ * D_, tokD, bq, bk, bv, nullptr, 0);

    // 4) scores: logits = relu(qp@kp^T)/32 + mask   [per-batch M=N=2048,K=1024]
    //    BM=BN=256, warps 2x4, 64KB LDS -> 2 blocks/CU
    gemm4p_kernel<8, 4, 2, 4, 1><<<dim3(8, 8, 4), 512, 0, stream>>>(
        qp, kp, logits, D_, D_, D_, S_,
        (size_t)S_ * D_, (size_t)S_ * D_, (size_t)S_ * S_,
        nullptr, nullptr, nullptr, mask, S_);

    // 5) vp -> vpT per batch (into qp region, dead after scores)
    transpose_bf16_kernel<<<dim3(D_ / 64, S_ / 64, B_), 256, 0, stream>>>(vp, vpT);

    // 6) PV: out = relu(logits @ vpT^T)   [per-batch M=2048,N=1024,K=2048], f32 out
    //    BM=256 BN=128, warps 4x2, 48KB LDS -> 3 blocks/CU
    gemm4p_kernel<4, 4, 4, 2, 2><<<dim3(8, 8, 4), 512, 0, stream>>>(
        logits, vpT, out, S_, S_, S_, D_,
        (size_t)S_ * S_, (size_t)D_ * S_, (size_t)S_ * D_,
        nullptr, nullptr, nullptr, nullptr, 0);
}

// Round 5
// 353.600 us; speedup vs baseline: 1.6311x; 1.6311x over previous
//
#include <hip/hip_runtime.h>

// ScaledConvolutionalDotProduct: B=4, S=2048, D=1024
//   qp = relu(q@Wq + bq); kp = relu(k@Wk + bk); vp = relu(v@Wv + bv)
//   logits = relu(qp@kp^T)/32 + mask;  out = relu(logits@vp)
// Round 5: 4 FAT phases per 2 K-tiles (16-32 MFMA/wave/phase), counted vmcnt,
//          tail peel with drain (fixes r3 latent race), launch_bounds(512,2).

#define B_ 4
#define S_ 2048
#define D_ 1024

typedef __attribute__((ext_vector_type(8))) short short8;
typedef __attribute__((ext_vector_type(4))) float f32x4;
typedef const __attribute__((address_space(1))) void* gas1;
typedef __attribute__((address_space(3))) void* las3;

template <int V> struct IC { static constexpr int value = V; };

static __device__ __forceinline__ short f2bf(float x) {
    union { float f; unsigned u; } un; un.f = x;
    unsigned r = un.u + 0x7fff + ((un.u >> 16) & 1);
    return (short)(r >> 16);
}

// ---------------- fp32 -> bf16 convert, q/k/v fused (8 elems/thread) ----------------
__global__ void cvt3_kernel(const float* __restrict__ q, const float* __restrict__ k,
                            const float* __restrict__ v, short* __restrict__ out) {
    const float* in = (blockIdx.y == 0) ? q : ((blockIdx.y == 1) ? k : v);
    size_t i = ((size_t)blockIdx.x * blockDim.x + threadIdx.x) * 8;
    short* o = out + (size_t)blockIdx.y * ((size_t)B_ * S_ * D_);
    float4 a = *(const float4*)(in + i);
    float4 b = *(const float4*)(in + i + 4);
    short8 r;
    r[0] = f2bf(a.x); r[1] = f2bf(a.y); r[2] = f2bf(a.z); r[3] = f2bf(a.w);
    r[4] = f2bf(b.x); r[5] = f2bf(b.y); r[6] = f2bf(b.z); r[7] = f2bf(b.w);
    *(short8*)(o + i) = r;
}

// ---------------- W [d][e] fp32 -> W^T [e][d] bf16 ----------------
__global__ void make_wT_kernel(const float* __restrict__ Wq, const float* __restrict__ Wk,
                               const float* __restrict__ Wv, short* __restrict__ wT) {
    const float* W = (blockIdx.z == 0) ? Wq : ((blockIdx.z == 1) ? Wk : Wv);
    short* o = wT + (size_t)blockIdx.z * D_ * D_;
    __shared__ float t[32][33];
    int bx = blockIdx.x, by = blockIdx.y;
    int tx = threadIdx.x & 31, ty = threadIdx.x >> 5;   // 32 x 8
    #pragma unroll
    for (int r = ty; r < 32; r += 8)
        t[r][tx] = W[(size_t)(by * 32 + r) * D_ + bx * 32 + tx];
    __syncthreads();
    #pragma unroll
    for (int r = ty; r < 32; r += 8)
        o[(size_t)(bx * 32 + r) * D_ + by * 32 + tx] = f2bf(t[tx][r]);
}

// ---------------- vp [b][s][e] -> vpT [b][e][s] (bf16) ----------------
__global__ void transpose_bf16_kernel(const short* __restrict__ in, short* __restrict__ out) {
    __shared__ short t[64][65];
    int b = blockIdx.z;
    int e0 = blockIdx.x * 64, s0 = blockIdx.y * 64;
    const short* src = in + (size_t)b * S_ * D_;
    short* dst = out + (size_t)b * D_ * S_;
    int tx = threadIdx.x & 63, ty = threadIdx.x >> 6;   // 64 x 4
    #pragma unroll
    for (int r = ty; r < 64; r += 4)
        t[r][tx] = src[(size_t)(s0 + r) * D_ + e0 + tx];
    __syncthreads();
    #pragma unroll
    for (int r = ty; r < 64; r += 4)
        dst[(size_t)(e0 + r) * S_ + s0 + tx] = t[tx][r];
}

// ---------------- fat-4-phase GEMM: C = epilogue(A * B^T), A:[M,K] B:[N,K] bf16 ----
// 8 waves (2 x 4), BM=256, BN=64*N_REP (128/256), BK=64, double-buffered LDS.
// Per 2 K-tiles: 4 fat phases, each = one M-half x full BK (16..32 MFMA/wave).
// Stage schedule: fp1 stages A(par1,t1); fp2 stages B(par0,t2) + vmcnt(VMN);
//                 fp3 stages A(par0,t2); fp4 stages B(par1,t3) + vmcnt(VMN).
// Last iteration peeled with full drain (no in-flight loads into first read).
// EPI 0: bf16 = relu(acc + bias[n]); EPI 1: bf16 = relu(acc)/32 + mask; EPI 2: f32 = relu(acc)
template <int M_REP, int N_REP, int EPI>
__global__ __launch_bounds__(512, 2)
void gemmf4_kernel(const short* __restrict__ A, const short* __restrict__ B, void* __restrict__ Cv,
                   int K, int lda, int ldb, int ldc,
                   size_t sA, size_t sB, size_t sC,
                   const float* __restrict__ bias0, const float* __restrict__ bias1,
                   const float* __restrict__ bias2,
                   const float* __restrict__ mask, int ldmask) {
    constexpr int BM = 16 * M_REP * 2;       // 256
    constexpr int BN = 16 * N_REP * 4;       // 128 or 256
    constexpr int AR = BM / 64;              // stage rounds (64 rows per 512thr x 16B round)
    constexpr int BR = BN / 64;
    constexpr int VMN = BR * 1;              // B gl_lds issues per tile (per thread)

    __shared__ short As[2][BM * 64];
    __shared__ short Bs[2][BN * 64];

    // T1: bijective XCD swizzle on flat block id (nwg % 8 == 0 for all our launches)
    const int gx = gridDim.x, gy = gridDim.y;
    const int nwg = gx * gy * gridDim.z;
    const int flat = blockIdx.x + gx * (blockIdx.y + gy * blockIdx.z);
    const int swz = (flat & 7) * (nwg >> 3) + (flat >> 3);
    const int bx = swz % gx;
    const int rem = swz / gx;
    const int by = rem % gy;
    const int bz = rem / gy;

    const int m0 = bx * BM, n0 = by * BN;
    const short* Ab = A + (size_t)bz * sA;
    const short* Bb = B + (size_t)bz * sB;

    const int tid = threadIdx.x;
    const int lane = tid & 63;
    const int w = tid >> 6;                  // wave 0..7
    const int wr = w >> 2, wc = w & 3;       // 2 x 4 wave grid
    const int lr16 = lane & 15, kq = lane >> 4;
    const int NT = K >> 6;                   // K-tiles of 64 (even, >= 2)

    // source-side swizzle: slot(tid&7) ^= row&7 (= (tid>>3)&7), 16B slots of a 128B row
    const int csrc = (((tid & 7) ^ ((tid >> 3) & 7)) << 3);

    auto stageA = [&](int par, int kt) {
        #pragma unroll
        for (int R = 0; R < AR; ++R) {
            int row = R * 64 + (tid >> 3);
            const short* src = Ab + (size_t)(m0 + row) * lda + kt * 64 + csrc;
            __builtin_amdgcn_global_load_lds((gas1)src, (las3)&As[par][R * 4096 + tid * 8], 16, 0, 0);
        }
    };
    auto stageB = [&](int par, int kt) {
        #pragma unroll
        for (int R = 0; R < BR; ++R) {
            int row = R * 64 + (tid >> 3);
            const short* src = Bb + (size_t)(n0 + row) * ldb + kt * 64 + csrc;
            __builtin_amdgcn_global_load_lds((gas1)src, (las3)&Bs[par][R * 4096 + tid * 8], 16, 0, 0);
        }
    };
    // swizzled ds_read_b128 of one 16x32 MFMA fragment
    auto ldA = [&](int par, int mi, int ks) -> short8 {
        int row = wr * (BM / 2) + mi * 16 + lr16;
        int col = (ks * 32 + kq * 8) ^ ((lr16 & 7) * 8);
        return *(const short8*)&As[par][row * 64 + col];
    };
    auto ldB = [&](int par, int ni, int ks) -> short8 {
        int row = wc * (16 * N_REP) + ni * 16 + lr16;
        int col = (ks * 32 + kq * 8) ^ ((lr16 & 7) * 8);
        return *(const short8*)&Bs[par][row * 64 + col];
    };

    f32x4 acc[M_REP][N_REP] = {};
    short8 bfr[2][N_REP];

    // prologue: A(0)<-t0, B(0)<-t0, B(1)<-t1; leave B(1) in flight
    stageA(0, 0); stageB(0, 0); stageB(1, 1);
    if constexpr (VMN == 4) asm volatile("s_waitcnt vmcnt(4)" ::: "memory");
    else                    asm volatile("s_waitcnt vmcnt(2)" ::: "memory");
    __builtin_amdgcn_s_barrier();

    // fat phase: one M-half x full BK=64.  vmMode: 0 none, 1 counted, 2 drain
    auto fphase = [&](int par, auto mhC, auto stageF, auto vmC) {
        constexpr int mh = decltype(mhC)::value;
        constexpr int vmMode = decltype(vmC)::value;
        short8 a[2][M_REP / 2];
        #pragma unroll
        for (int ks = 0; ks < 2; ++ks)
            #pragma unroll
            for (int m = 0; m < M_REP / 2; ++m)
                a[ks][m] = ldA(par, mh * (M_REP / 2) + m, ks);
        if constexpr (mh == 0) {
            #pragma unroll
            for (int ks = 0; ks < 2; ++ks)
                #pragma unroll
                for (int n = 0; n < N_REP; ++n)
                    bfr[ks][n] = ldB(par, n, ks);
        }
        stageF();
        __builtin_amdgcn_s_barrier();
        asm volatile("s_waitcnt lgkmcnt(0)" ::: "memory");
        __builtin_amdgcn_s_setprio(1);
        #pragma unroll
        for (int ks = 0; ks < 2; ++ks)
            #pragma unroll
            for (int m = 0; m < M_REP / 2; ++m)
                #pragma unroll
                for (int n = 0; n < N_REP; ++n)
                    acc[mh * (M_REP / 2) + m][n] =
                        __builtin_amdgcn_mfma_f32_16x16x32_bf16(a[ks][m], bfr[ks][n],
                                                                acc[mh * (M_REP / 2) + m][n], 0, 0, 0);
        __builtin_amdgcn_s_setprio(0);
        if constexpr (vmMode == 1) {
            if constexpr (VMN == 4) asm volatile("s_waitcnt vmcnt(4)" ::: "memory");
            else                    asm volatile("s_waitcnt vmcnt(2)" ::: "memory");
        } else if constexpr (vmMode == 2) {
            asm volatile("s_waitcnt vmcnt(0)" ::: "memory");
        }
        __builtin_amdgcn_s_barrier();
    };

    #pragma unroll 1
    for (int I = 0; I < (NT >> 1) - 1; ++I) {
        const int t1 = 2 * I + 1, t2 = 2 * I + 2, t3 = 2 * I + 3;
        fphase(0, IC<0>{}, [&] { stageA(1, t1); }, IC<0>{});
        fphase(0, IC<1>{}, [&] { stageB(0, t2); }, IC<1>{});
        fphase(1, IC<0>{}, [&] { stageA(0, t2); }, IC<0>{});
        fphase(1, IC<1>{}, [&] { stageB(1, t3); }, IC<1>{});
    }
    // peeled last iteration (tiles NT-2, NT-1): stage only A(1, NT-1), then drain
    fphase(0, IC<0>{}, [&] { stageA(1, NT - 1); }, IC<0>{});
    fphase(0, IC<1>{}, [&] {}, IC<2>{});
    fphase(1, IC<0>{}, [&] {}, IC<0>{});
    fphase(1, IC<1>{}, [&] {}, IC<0>{});

    // epilogue: C/D layout col=lane&15, row=(lane>>4)*4+j  [m89-verified]
    short* Cs = (short*)Cv + (size_t)bz * sC;
    float* Cf = (float*)Cv + (size_t)bz * sC;
    const float* bias = (EPI == 0) ? ((bz == 0) ? bias0 : ((bz == 1) ? bias1 : bias2)) : nullptr;
    #pragma unroll
    for (int mi = 0; mi < M_REP; ++mi) {
        #pragma unroll
        for (int ni = 0; ni < N_REP; ++ni) {
            int n = n0 + wc * (16 * N_REP) + ni * 16 + lr16;
            int mb = m0 + wr * (BM / 2) + mi * 16 + kq * 4;
            #pragma unroll
            for (int j = 0; j < 4; ++j) {
                int m = mb + j;
                float val = acc[mi][ni][j];
                if constexpr (EPI == 0) {
                    val = fmaxf(val + bias[n], 0.f);
                    Cs[(size_t)m * ldc + n] = f2bf(val);
                } else if constexpr (EPI == 1) {
                    val = fmaxf(val, 0.f) * 0.03125f + mask[(size_t)m * ldmask + n];
                    Cs[(size_t)m * ldc + n] = f2bf(val);
                } else {
                    Cf[(size_t)m * ldc + n] = fmaxf(val, 0.f);
                }
            }
        }
    }
}

extern "C" void kernel_launch(void* const* d_in, const int* in_sizes, int n_in,
                              void* d_out, int out_size, void* d_ws, size_t ws_size,
                              hipStream_t stream) {
    const float* q    = (const float*)d_in[0];
    const float* k    = (const float*)d_in[1];
    const float* v    = (const float*)d_in[2];
    const float* mask = (const float*)d_in[3];
    const float* Wq   = (const float*)d_in[4];
    const float* Wk   = (const float*)d_in[5];
    const float* Wv   = (const float*)d_in[6];
    const float* bq   = (const float*)d_in[7];
    const float* bk   = (const float*)d_in[8];
    const float* bv   = (const float*)d_in[9];
    float* out = (float*)d_out;

    char* ws = (char*)d_ws;
    // layout (bytes):
    //   wT     @ 0          : 3*1024*1024*2   = 6,291,456
    //   qkv_bf @ 6,291,456  : 3*8192*1024*2   = 50,331,648  (dead after projections)
    //   logits @ 6,291,456  : 4*2048*2048*2   = 33,554,432  (overlay on qkv_bf)
    //   qkvp   @ 56,623,104 : 3*8192*1024*2   = 50,331,648  (qp|kp|vp)
    //   vpT    @ 56,623,104 : overlay on qp (qp dead after scores)
    //   total 106,954,752
    short* wT     = (short*)(ws);
    short* qkv_bf = (short*)(ws + 6291456);
    short* logits = (short*)(ws + 6291456);
    short* qkvp   = (short*)(ws + 56623104);
    short* qp     = qkvp;
    short* kp     = qkvp + (size_t)B_ * S_ * D_;
    short* vp     = qkvp + 2 * (size_t)B_ * S_ * D_;
    short* vpT    = qp;   // overlay (qp dead after scores)

    const size_t tok = (size_t)B_ * S_;            // 8192
    const size_t tokD = tok * D_;                  // 8,388,608

    // 1) W -> W^T bf16
    make_wT_kernel<<<dim3(32, 32, 3), 256, 0, stream>>>(Wq, Wk, Wv, wT);

    // 2) q/k/v -> bf16 (one fused launch)
    cvt3_kernel<<<dim3(tokD / 8 / 256, 3), 256, 0, stream>>>(q, k, v, qkv_bf);

    // 3) projections, batched z=3: qp/kp/vp = relu(x @ W + b)  [M=8192,N=1024,K=1024]
    gemmf4_kernel<8, 2, 0><<<dim3(32, 8, 3), 512, 0, stream>>>(
        qkv_bf, wT, qkvp, D_, D_, D_, D_,
        tokD, (size_t)D_ * D_, tokD, bq, bk, bv, nullptr, 0);

    // 4) scores: logits = relu(qp@kp^T)/32 + mask   [per-batch M=N=2048,K=1024]
    gemmf4_kernel<8, 4, 1><<<dim3(8, 8, 4), 512, 0, stream>>>(
        qp, kp, logits, D_, D_, D_, S_,
        (size_t)S_ * D_, (size_t)S_ * D_, (size_t)S_ * S_,
        nullptr, nullptr, nullptr, mask, S_);

    // 5) vp -> vpT per batch (into qp region, dead after scores)
    transpose_bf16_kernel<<<dim3(D_ / 64, S_ / 64, B_), 256, 0, stream>>>(vp, vpT);

    // 6) PV: out = relu(logits @ vpT^T)   [per-batch M=2048,N=1024,K=2048], f32 out
    gemmf4_kernel<8, 2, 2><<<dim3(8, 8, 4), 512, 0, stream>>>(
        logits, vpT, out, S_, S_, S_, D_,
        (size_t)S_ * S_, (size_t)D_ * S_, (size_t)S_ * D_,
        nullptr, nullptr, nullptr, nullptr, 0);
}

// Round 7
// 344.680 us; speedup vs baseline: 1.6734x; 1.0259x over previous
//
#include <hip/hip_runtime.h>

// ScaledConvolutionalDotProduct: B=4, S=2048, D=1024
//   qp = relu(q@Wq + bq); kp = relu(k@Wk + bk); vp = relu(v@Wv + bv)
//   logits = relu(qp@kp^T)/32 + mask;  out = relu(logits@vp)
// Round 7 (= round 6 resubmit after infra failure): BK=32 triple-buffered GEMM,
// wave grid 4x2, 72KB LDS -> 2 blocks/CU, counted vmcnt(3), 2 barriers/tile.

#define B_ 4
#define S_ 2048
#define D_ 1024

typedef __attribute__((ext_vector_type(8))) short short8;
typedef __attribute__((ext_vector_type(4))) float f32x4;
typedef const __attribute__((address_space(1))) void* gas1;
typedef __attribute__((address_space(3))) void* las3;

static __device__ __forceinline__ short f2bf(float x) {
    union { float f; unsigned u; } un; un.f = x;
    unsigned r = un.u + 0x7fff + ((un.u >> 16) & 1);
    return (short)(r >> 16);
}

// ---------------- fp32 -> bf16 convert, q/k/v fused (8 elems/thread) ----------------
__global__ void cvt3_kernel(const float* __restrict__ q, const float* __restrict__ k,
                            const float* __restrict__ v, short* __restrict__ out) {
    const float* in = (blockIdx.y == 0) ? q : ((blockIdx.y == 1) ? k : v);
    size_t i = ((size_t)blockIdx.x * blockDim.x + threadIdx.x) * 8;
    short* o = out + (size_t)blockIdx.y * ((size_t)B_ * S_ * D_);
    float4 a = *(const float4*)(in + i);
    float4 b = *(const float4*)(in + i + 4);
    short8 r;
    r[0] = f2bf(a.x); r[1] = f2bf(a.y); r[2] = f2bf(a.z); r[3] = f2bf(a.w);
    r[4] = f2bf(b.x); r[5] = f2bf(b.y); r[6] = f2bf(b.z); r[7] = f2bf(b.w);
    *(short8*)(o + i) = r;
}

// ---------------- W [d][e] fp32 -> W^T [e][d] bf16 ----------------
__global__ void make_wT_kernel(const float* __restrict__ Wq, const float* __restrict__ Wk,
                               const float* __restrict__ Wv, short* __restrict__ wT) {
    const float* W = (blockIdx.z == 0) ? Wq : ((blockIdx.z == 1) ? Wk : Wv);
    short* o = wT + (size_t)blockIdx.z * D_ * D_;
    __shared__ float t[32][33];
    int bx = blockIdx.x, by = blockIdx.y;
    int tx = threadIdx.x & 31, ty = threadIdx.x >> 5;   // 32 x 8
    #pragma unroll
    for (int r = ty; r < 32; r += 8)
        t[r][tx] = W[(size_t)(by * 32 + r) * D_ + bx * 32 + tx];
    __syncthreads();
    #pragma unroll
    for (int r = ty; r < 32; r += 8)
        o[(size_t)(bx * 32 + r) * D_ + by * 32 + tx] = f2bf(t[tx][r]);
}

// ---------------- vp [b][s][e] -> vpT [b][e][s] (bf16) ----------------
__global__ void transpose_bf16_kernel(const short* __restrict__ in, short* __restrict__ out) {
    __shared__ short t[64][65];
    int b = blockIdx.z;
    int e0 = blockIdx.x * 64, s0 = blockIdx.y * 64;
    const short* src = in + (size_t)b * S_ * D_;
    short* dst = out + (size_t)b * D_ * S_;
    int tx = threadIdx.x & 63, ty = threadIdx.x >> 6;   // 64 x 4
    #pragma unroll
    for (int r = ty; r < 64; r += 4)
        t[r][tx] = src[(size_t)(s0 + r) * D_ + e0 + tx];
    __syncthreads();
    #pragma unroll
    for (int r = ty; r < 64; r += 4)
        dst[(size_t)(e0 + r) * S_ + s0 + tx] = t[tx][r];
}

// -------- triple-buffered BK=32 GEMM: C = epilogue(A * B^T), A:[M,K] B:[N,K] bf16 ----
// 8 waves, grid WM=4 x WN=2. BM=256, BN=128, M_REP=N_REP=4.
// LDS = 3 x (16KB A + 8KB B) = 72KB -> 2 blocks/CU.
// Per tile t: read buf r0 (holds t), stage t+2 into buf r2, counted vmcnt(3).
// Race safety: buf r2's old content (tile t-1) was last read at tile t-1, drained by
// lgkmcnt(0) before that phase's MFMA, which precedes its end barrier; stage issues
// only after that barrier -> no write-before-read. vmcnt(3) at tile end leaves only
// t+2's 3 issues outstanding -> t+1 fully landed (vmcnt retires in issue order).
// EPI 0: bf16 = relu(acc + bias[n]); EPI 1: bf16 = relu(acc)/32 + mask; EPI 2: f32 = relu(acc)
template <int EPI>
__global__ __launch_bounds__(512, 2)
void gemm3b_kernel(const short* __restrict__ A, const short* __restrict__ B, void* __restrict__ Cv,
                   int K, int lda, int ldb, int ldc,
                   size_t sA, size_t sB, size_t sC,
                   const float* __restrict__ bias0, const float* __restrict__ bias1,
                   const float* __restrict__ bias2,
                   const float* __restrict__ mask, int ldmask) {
    constexpr int BM = 256, BN = 128;
    constexpr int ASZ = BM * 32;             // 8192 shorts (16KB)
    constexpr int BSZ = BN * 32;             // 4096 shorts (8KB)

    __shared__ short As[3][ASZ];
    __shared__ short Bs[3][BSZ];

    // T1: bijective XCD swizzle on flat block id (nwg % 8 == 0 for all our launches)
    const int gx = gridDim.x, gy = gridDim.y;
    const int nwg = gx * gy * gridDim.z;
    const int flat = blockIdx.x + gx * (blockIdx.y + gy * blockIdx.z);
    const int swz = (flat & 7) * (nwg >> 3) + (flat >> 3);
    const int bx = swz % gx;
    const int rem = swz / gx;
    const int by = rem % gy;
    const int bz = rem / gy;

    const int m0 = bx * BM, n0 = by * BN;
    const short* Ab = A + (size_t)bz * sA;
    const short* Bb = B + (size_t)bz * sB;

    const int tid = threadIdx.x;
    const int lane = tid & 63;
    const int w = tid >> 6;                  // wave 0..7
    const int wr = w >> 1, wc = w & 1;       // 4 x 2 wave grid
    const int lr16 = lane & 15, kq = lane >> 4;
    const int NT = K >> 5;                   // K-tiles of 32

    // source-side inverse swizzle: within a 32-short row, slot(tid&3) ^= (row>>1)&3
    // (row staged by thread = tid>>2 per round; (row>>1)&3 = (tid>>3)&3)
    const int csrc = (((tid & 3) ^ ((tid >> 3) & 3)) << 3);

    auto stageA = [&](int buf, int kt) {
        if (kt >= NT) return;
        #pragma unroll
        for (int R = 0; R < 2; ++R) {
            int row = R * 128 + (tid >> 2);
            const short* src = Ab + (size_t)(m0 + row) * lda + kt * 32 + csrc;
            __builtin_amdgcn_global_load_lds((gas1)src, (las3)&As[buf][R * 4096 + tid * 8], 16, 0, 0);
        }
    };
    auto stageB = [&](int buf, int kt) {
        if (kt >= NT) return;
        int row = tid >> 2;
        const short* src = Bb + (size_t)(n0 + row) * ldb + kt * 32 + csrc;
        __builtin_amdgcn_global_load_lds((gas1)src, (las3)&Bs[buf][tid * 8], 16, 0, 0);
    };
    // swizzled ds_read_b128 of one 16x32 fragment: col slot = kq ^ ((row>>1)&3)
    auto ldA = [&](int buf, int mi) -> short8 {
        int row = wr * 64 + mi * 16 + lr16;
        int col = (kq ^ ((row >> 1) & 3)) << 3;
        return *(const short8*)&As[buf][row * 32 + col];
    };
    auto ldB = [&](int buf, int ni) -> short8 {
        int row = wc * 64 + ni * 16 + lr16;
        int col = (kq ^ ((row >> 1) & 3)) << 3;
        return *(const short8*)&Bs[buf][row * 32 + col];
    };

    f32x4 acc[4][4] = {};

    // prologue: t0 -> buf0, t1 -> buf1; leave t1 in flight
    stageA(0, 0); stageB(0, 0);
    stageA(1, 1); stageB(1, 1);
    asm volatile("s_waitcnt vmcnt(3)" ::: "memory");
    __builtin_amdgcn_s_barrier();

    int r0 = 0, r1 = 1, r2 = 2;
    #pragma unroll 1
    for (int t = 0; t < NT; ++t) {
        // ---- phase A: M-half 0 (mi 0,1) + B frags; stage A(t+2) ----
        short8 a0 = ldA(r0, 0), a1 = ldA(r0, 1);
        short8 b0 = ldB(r0, 0), b1 = ldB(r0, 1), b2 = ldB(r0, 2), b3 = ldB(r0, 3);
        stageA(r2, t + 2);
        asm volatile("s_waitcnt lgkmcnt(0)" ::: "memory");
        __builtin_amdgcn_s_setprio(1);
        acc[0][0] = __builtin_amdgcn_mfma_f32_16x16x32_bf16(a0, b0, acc[0][0], 0, 0, 0);
        acc[0][1] = __builtin_amdgcn_mfma_f32_16x16x32_bf16(a0, b1, acc[0][1], 0, 0, 0);
        acc[0][2] = __builtin_amdgcn_mfma_f32_16x16x32_bf16(a0, b2, acc[0][2], 0, 0, 0);
        acc[0][3] = __builtin_amdgcn_mfma_f32_16x16x32_bf16(a0, b3, acc[0][3], 0, 0, 0);
        acc[1][0] = __builtin_amdgcn_mfma_f32_16x16x32_bf16(a1, b0, acc[1][0], 0, 0, 0);
        acc[1][1] = __builtin_amdgcn_mfma_f32_16x16x32_bf16(a1, b1, acc[1][1], 0, 0, 0);
        acc[1][2] = __builtin_amdgcn_mfma_f32_16x16x32_bf16(a1, b2, acc[1][2], 0, 0, 0);
        acc[1][3] = __builtin_amdgcn_mfma_f32_16x16x32_bf16(a1, b3, acc[1][3], 0, 0, 0);
        __builtin_amdgcn_s_setprio(0);
        __builtin_amdgcn_s_barrier();

        // ---- phase B: M-half 1 (mi 2,3); stage B(t+2); counted vmcnt ----
        short8 a2 = ldA(r0, 2), a3 = ldA(r0, 3);
        stageB(r2, t + 2);
        asm volatile("s_waitcnt lgkmcnt(0)" ::: "memory");
        __builtin_amdgcn_s_setprio(1);
        acc[2][0] = __builtin_amdgcn_mfma_f32_16x16x32_bf16(a2, b0, acc[2][0], 0, 0, 0);
        acc[2][1] = __builtin_amdgcn_mfma_f32_16x16x32_bf16(a2, b1, acc[2][1], 0, 0, 0);
        acc[2][2] = __builtin_amdgcn_mfma_f32_16x16x32_bf16(a2, b2, acc[2][2], 0, 0, 0);
        acc[2][3] = __builtin_amdgcn_mfma_f32_16x16x32_bf16(a2, b3, acc[2][3], 0, 0, 0);
        acc[3][0] = __builtin_amdgcn_mfma_f32_16x16x32_bf16(a3, b0, acc[3][0], 0, 0, 0);
        acc[3][1] = __builtin_amdgcn_mfma_f32_16x16x32_bf16(a3, b1, acc[3][1], 0, 0, 0);
        acc[3][2] = __builtin_amdgcn_mfma_f32_16x16x32_bf16(a3, b2, acc[3][2], 0, 0, 0);
        acc[3][3] = __builtin_amdgcn_mfma_f32_16x16x32_bf16(a3, b3, acc[3][3], 0, 0, 0);
        __builtin_amdgcn_s_setprio(0);
        asm volatile("s_waitcnt vmcnt(3)" ::: "memory");
        __builtin_amdgcn_s_barrier();

        int tmp = r0; r0 = r1; r1 = r2; r2 = tmp;
    }

    // epilogue: C/D layout col=lane&15, row=(lane>>4)*4+j  [m89-verified]
    short* Cs = (short*)Cv + (size_t)bz * sC;
    float* Cf = (float*)Cv + (size_t)bz * sC;
    const float* bias = (EPI == 0) ? ((bz == 0) ? bias0 : ((bz == 1) ? bias1 : bias2)) : nullptr;
    #pragma unroll
    for (int mi = 0; mi < 4; ++mi) {
        #pragma unroll
        for (int ni = 0; ni < 4; ++ni) {
            int n = n0 + wc * 64 + ni * 16 + lr16;
            int mb = m0 + wr * 64 + mi * 16 + kq * 4;
            #pragma unroll
            for (int j = 0; j < 4; ++j) {
                int m = mb + j;
                float val = acc[mi][ni][j];
                if constexpr (EPI == 0) {
                    val = fmaxf(val + bias[n], 0.f);
                    Cs[(size_t)m * ldc + n] = f2bf(val);
                } else if constexpr (EPI == 1) {
                    val = fmaxf(val, 0.f) * 0.03125f + mask[(size_t)m * ldmask + n];
                    Cs[(size_t)m * ldc + n] = f2bf(val);
                } else {
                    Cf[(size_t)m * ldc + n] = fmaxf(val, 0.f);
                }
            }
        }
    }
}

extern "C" void kernel_launch(void* const* d_in, const int* in_sizes, int n_in,
                              void* d_out, int out_size, void* d_ws, size_t ws_size,
                              hipStream_t stream) {
    const float* q    = (const float*)d_in[0];
    const float* k    = (const float*)d_in[1];
    const float* v    = (const float*)d_in[2];
    const float* mask = (const float*)d_in[3];
    const float* Wq   = (const float*)d_in[4];
    const float* Wk   = (const float*)d_in[5];
    const float* Wv   = (const float*)d_in[6];
    const float* bq   = (const float*)d_in[7];
    const float* bk   = (const float*)d_in[8];
    const float* bv   = (const float*)d_in[9];
    float* out = (float*)d_out;

    char* ws = (char*)d_ws;
    // layout (bytes):
    //   wT     @ 0          : 3*1024*1024*2   = 6,291,456
    //   qkv_bf @ 6,291,456  : 3*8192*1024*2   = 50,331,648  (dead after projections)
    //   logits @ 6,291,456  : 4*2048*2048*2   = 33,554,432  (overlay on qkv_bf)
    //   qkvp   @ 56,623,104 : 3*8192*1024*2   = 50,331,648  (qp|kp|vp)
    //   vpT    @ 56,623,104 : overlay on qp (qp dead after scores)
    //   total 106,954,752
    short* wT     = (short*)(ws);
    short* qkv_bf = (short*)(ws + 6291456);
    short* logits = (short*)(ws + 6291456);
    short* qkvp   = (short*)(ws + 56623104);
    short* qp     = qkvp;
    short* kp     = qkvp + (size_t)B_ * S_ * D_;
    short* vp     = qkvp + 2 * (size_t)B_ * S_ * D_;
    short* vpT    = qp;   // overlay (qp dead after scores)

    const size_t tok = (size_t)B_ * S_;            // 8192
    const size_t tokD = tok * D_;                  // 8,388,608

    // 1) W -> W^T bf16
    make_wT_kernel<<<dim3(32, 32, 3), 256, 0, stream>>>(Wq, Wk, Wv, wT);

    // 2) q/k/v -> bf16 (one fused launch)
    cvt3_kernel<<<dim3(tokD / 8 / 256, 3), 256, 0, stream>>>(q, k, v, qkv_bf);

    // 3) projections, batched z=3: qp/kp/vp = relu(x @ W + b)  [M=8192,N=1024,K=1024]
    gemm3b_kernel<0><<<dim3(32, 8, 3), 512, 0, stream>>>(
        qkv_bf, wT, qkvp, D_, D_, D_, D_,
        tokD, (size_t)D_ * D_, tokD, bq, bk, bv, nullptr, 0);

    // 4) scores: logits = relu(qp@kp^T)/32 + mask   [per-batch M=N=2048,K=1024]
    gemm3b_kernel<1><<<dim3(8, 16, 4), 512, 0, stream>>>(
        qp, kp, logits, D_, D_, D_, S_,
        (size_t)S_ * D_, (size_t)S_ * D_, (size_t)S_ * S_,
        nullptr, nullptr, nullptr, mask, S_);

    // 5) vp -> vpT per batch (into qp region, dead after scores)
    transpose_bf16_kernel<<<dim3(D_ / 64, S_ / 64, B_), 256, 0, stream>>>(vp, vpT);

    // 6) PV: out = relu(logits @ vpT^T)   [per-batch M=2048,N=1024,K=2048], f32 out
    gemm3b_kernel<2><<<dim3(8, 8, 4), 512, 0, stream>>>(
        logits, vpT, out, S_, S_, S_, D_,
        (size_t)S_ * S_, (size_t)D_ * S_, (size_t)S_ * D_,
        nullptr, nullptr, nullptr, nullptr, 0);
}